// Round 19
// baseline (229.548 us; speedup 1.0000x reference)
//
#include <hip/hip_runtime.h>
#include <hip/hip_bf16.h>
#include <stdint.h>

#define T_TOK 4096
#define HID   7168
#define N0    2112
#define N0P   2176
#define QL    1536
#define KVL   512
#define ROPE  64
#define NQ    3072
#define H     16
#define NOPE  128
#define SLOTS 16384

#define N40 ((N0 * HID) / 4)
#define N41 ((NQ * QL) / 4)
#define NWKC (H * KVL * NOPE)
#define PREP0_BLOCKS ((N40 + 255) / 256)
#define ZKV4  ((SLOTS - T_TOK) * KVL / 4)
#define ZKVR4 ((SLOTS - T_TOK) * ROPE / 4)
#define PTOT (N41 + NWKC + ZKV4 + ZKVR4)
#define PREP_TRAIL 1024
#define NGEMM0 ((T_TOK / 128) * (N0P / 128))

typedef int   v4i __attribute__((ext_vector_type(4)));
typedef short v8s __attribute__((ext_vector_type(8)));
typedef float v4f __attribute__((ext_vector_type(4)));

typedef const __attribute__((address_space(1))) void g_void_t;
typedef __attribute__((address_space(3))) void lds_void_t;

__device__ __forceinline__ void gload16(const void* gp, void* lp) {
    __builtin_amdgcn_global_load_lds((g_void_t*)gp, (lds_void_t*)lp, 16, 0, 0);
}

__device__ __forceinline__ int quanti(float v, float qs, float qo) {
    float r = rintf(v / qs + qo);          // round half-to-even, matches jnp.round
    r = fminf(127.f, fmaxf(-128.f, r));
    return (int)r;
}

__device__ __forceinline__ unsigned int pack4(int a, int b, int c, int d) {
    return (unsigned int)(a & 255) | ((unsigned int)(b & 255) << 8) |
           ((unsigned int)(c & 255) << 16) | ((unsigned int)(d & 255) << 24);
}

__device__ __forceinline__ unsigned short f2bf(float v) {
    __hip_bfloat16 b = __float2bfloat16(v);
    return *reinterpret_cast<unsigned short*>(&b);
}

__device__ __forceinline__ float bf2f(unsigned short u) {
    unsigned int x = ((unsigned int)u) << 16;
    return *reinterpret_cast<float*>(&x);
}

// -- prep0: rms+quant rows [0,T) | wdqkv pack (only what GEMM0 needs) --------
__global__ __launch_bounds__(256) void prep_rms_kernel(
    const float* __restrict__ x, const float* __restrict__ g, const float* __restrict__ b,
    const float* __restrict__ qs_p, const int* __restrict__ qo_p,
    unsigned int* __restrict__ x8,
    const int* __restrict__ wdqkv, unsigned int* __restrict__ w0)
{
    const int tid = threadIdx.x;
    if (blockIdx.x >= T_TOK) {
        int i = (blockIdx.x - T_TOK) * 256 + tid;
        if (i < N40) {
            int4 v = ((const int4*)wdqkv)[i];
            w0[i] = pack4(v.x, v.y, v.z, v.w);
        }
        return;
    }
    // rmsnorm + quant row
    __shared__ float red[4];
    const int t = blockIdx.x;
    const float4* xr = (const float4*)(x + (size_t)t * HID);
    float4 vs[7];
    float ss = 0.f;
#pragma unroll
    for (int i = 0; i < 7; i++) {
        float4 v = xr[i * 256 + tid];
        vs[i] = v;
        ss += v.x * v.x + v.y * v.y + v.z * v.z + v.w * v.w;
    }
#pragma unroll
    for (int off = 32; off > 0; off >>= 1) ss += __shfl_down(ss, off);
    if ((tid & 63) == 0) red[tid >> 6] = ss;
    __syncthreads();
    float s = red[0] + red[1] + red[2] + red[3];
    float rs = rsqrtf(s / (float)HID + 1e-6f);
    float qs = qs_p[0];
    float qo = (float)qo_p[0];
    const float4* gr = (const float4*)g;
    const float4* br = (const float4*)b;
    unsigned int* orow = x8 + (size_t)t * (HID / 4);
#pragma unroll
    for (int i = 0; i < 7; i++) {
        int j = i * 256 + tid;
        float4 v = vs[i], gg = gr[j], bb = br[j];
        int q0 = quanti(v.x * rs * gg.x + bb.x, qs, qo);
        int q1 = quanti(v.y * rs * gg.y + bb.y, qs, qo);
        int q2 = quanti(v.z * rs * gg.z + bb.z, qs, qo);
        int q3 = quanti(v.w * rs * gg.w + bb.w, qs, qo);
        orow[j] = pack4(q0, q1, q2, q3);
    }
}

// ---------------- GEMM0: i8, BK=64, double-buffered, bf16 C ----------------
// BM=BN=128, BK=64, 512 threads = 8 waves (2x4), wave tile 64x32.
// M-FASTEST tile order (bm = wg&31, bn = wg>>5): each XCD's contiguous
// 68-block chunk becomes a ~2-col B slice (~2.7MB, L2-resident) x all 32
// m-tiles; A streams through the shared L3. Converts B staging loads from
// L3/HBM-latency misses to L2 hits in the latency-bound 2-phase loop.
// Blocks [ngemm, gridDim.x): trailing prep (w1 pack + wkc transpose +
// kv-tail zero) grid-striding under the GEMM.
__global__ __launch_bounds__(512, 8) void gemm_i8_db_kernel(
    const signed char* __restrict__ A, const signed char* __restrict__ B,
    const int* __restrict__ bias, const float* __restrict__ descale,
    unsigned short* __restrict__ C, int M, int N, int Np, int K, int ngemm,
    const int* __restrict__ wuq, const float* __restrict__ wkc,
    unsigned int* __restrict__ w1o, unsigned short* __restrict__ wkcb,
    float* __restrict__ kv_tail, float* __restrict__ kvr_tail)
{
    __shared__ __align__(16) signed char As[2][128 * 64];
    __shared__ __align__(16) signed char Bs[2][128 * 64];
    const int tid = threadIdx.x;

    if (blockIdx.x >= ngemm) {             // trailing prep blocks
        const int stride = (gridDim.x - ngemm) * 512;
        for (int i = (blockIdx.x - ngemm) * 512 + tid; i < PTOT; i += stride) {
            int j = i;
            if (j < N41) {
                int4 v = ((const int4*)wuq)[j];
                w1o[j] = pack4(v.x, v.y, v.z, v.w);
            } else if ((j -= N41) < NWKC) {
                int n = j & (NOPE - 1);
                int k = (j >> 7) & (KVL - 1);
                int h = j >> 16;
                wkcb[j] = f2bf(wkc[((size_t)h * NOPE + n) * KVL + k]);
            } else if ((j -= NWKC) < ZKV4) {
                ((float4*)kv_tail)[j] = make_float4(0.f, 0.f, 0.f, 0.f);
            } else {
                j -= ZKV4;
                ((float4*)kvr_tail)[j] = make_float4(0.f, 0.f, 0.f, 0.f);
            }
        }
        return;
    }

    const int lane = tid & 63, wid = tid >> 6;     // 8 waves
    const int wm = wid >> 2, wn = wid & 3;         // 2 x 4
    const int r16 = lane & 15, kq = lane >> 4;     // kq = 16B chunk 0..3

    // XCD-aware bijective swizzle over the ngemm GEMM blocks; M-FASTEST order
    const int nwg = ngemm;
    const int q = nwg >> 3, r = nwg & 7;
    const int xcd = blockIdx.x & 7, idx = blockIdx.x >> 3;
    const int wg = (xcd < r ? xcd * (q + 1) : r * (q + 1) + (xcd - r) * q) + idx;
    const int bm = (wg & 31) * 128, bn = (wg >> 5) * 128;   // ntm = 32 = M/128

    const int srow = tid >> 2;
    const int schunk = (tid & 3) ^ ((srow >> 1) & 3);
    const signed char* aSrc = A + (size_t)(bm + srow) * K + schunk * 16;
    const signed char* bSrc = B + (size_t)(bn + srow) * K + schunk * 16;

    auto STAGE = [&](int buf, int k0) {
        gload16(aSrc + k0, As[buf] + wid * 1024);
        gload16(bSrc + k0, Bs[buf] + wid * 1024);
    };

    int aOff[4], bOff[2];
#pragma unroll
    for (int mi = 0; mi < 4; mi++) {
        int ra = wm * 64 + mi * 16 + r16;
        aOff[mi] = ra * 64 + ((kq ^ ((ra >> 1) & 3)) * 16);
    }
#pragma unroll
    for (int ni = 0; ni < 2; ni++) {
        int rb = wn * 32 + ni * 16 + r16;
        bOff[ni] = rb * 64 + ((kq ^ ((rb >> 1) & 3)) * 16);
    }

    v4i acc[4][2];
#pragma unroll
    for (int i = 0; i < 4; i++)
#pragma unroll
        for (int j = 0; j < 2; j++) acc[i][j] = (v4i){0, 0, 0, 0};

    const int KT = K >> 6;
    STAGE(0, 0);
    for (int kt = 0; kt < KT; kt++) {
        const int cur = kt & 1;
        if (kt + 1 < KT) {
            STAGE(cur ^ 1, (kt + 1) << 6);
            asm volatile("s_waitcnt vmcnt(2)" ::: "memory");
        } else {
            asm volatile("s_waitcnt vmcnt(0)" ::: "memory");
        }
        __builtin_amdgcn_s_barrier();
        const signed char* as = As[cur];
        const signed char* bs = Bs[cur];
        v4i a[4], b[2];
#pragma unroll
        for (int mi = 0; mi < 4; mi++) a[mi] = *(const v4i*)(as + aOff[mi]);
#pragma unroll
        for (int ni = 0; ni < 2; ni++) b[ni] = *(const v4i*)(bs + bOff[ni]);
#pragma unroll
        for (int mi = 0; mi < 4; mi++)
#pragma unroll
            for (int ni = 0; ni < 2; ni++)
                acc[mi][ni] = __builtin_amdgcn_mfma_i32_16x16x64_i8(a[mi], b[ni], acc[mi][ni], 0, 0, 0);
        __builtin_amdgcn_s_barrier();
    }

#pragma unroll
    for (int ni = 0; ni < 2; ni++) {
        int col = bn + wn * 32 + ni * 16 + r16;
        int cc = col < N ? col : 0;
        float ds = descale[cc];
        int bv = bias[cc];
#pragma unroll
        for (int mi = 0; mi < 4; mi++) {
            int rowb = bm + wm * 64 + mi * 16 + kq * 4;
#pragma unroll
            for (int rr = 0; rr < 4; rr++) {
                C[(size_t)(rowb + rr) * Np + col] = f2bf((float)(acc[mi][ni][rr] + bv) * ds);
            }
        }
    }
}

// ---------------- GEMM1 + fused post1 epilogue, m-fastest order ------------
__global__ __launch_bounds__(512, 8) void gemm1_fused_kernel(
    const signed char* __restrict__ A, const signed char* __restrict__ B,
    const int* __restrict__ bias, const float* __restrict__ descale,
    const float* __restrict__ cs, const float* __restrict__ sn,
    unsigned short* __restrict__ qn, float* __restrict__ qrope,
    int K)
{
    __shared__ __align__(16) signed char As[2][128 * 64];
    __shared__ __align__(16) signed char Bs[2][128 * 64];
    const int tid = threadIdx.x;
    const int lane = tid & 63, wid = tid >> 6;     // 8 waves
    const int wm = wid >> 1, wn = wid & 1;         // 4(M) x 2(N)
    const int r16 = lane & 15, kq = lane >> 4;

    const int nwg = gridDim.x;
    const int q = nwg >> 3, r = nwg & 7;
    const int xcd = blockIdx.x & 7, idx = blockIdx.x >> 3;
    const int wg = (xcd < r ? xcd * (q + 1) : r * (q + 1) + (xcd - r) * q) + idx;
    const int bm = (wg & 31) * 128, bn = (wg >> 5) * 128;   // ntm = 32

    const int srow = tid >> 2;
    const int schunk = (tid & 3) ^ ((srow >> 1) & 3);
    const signed char* aSrc = A + (size_t)(bm + srow) * K + schunk * 16;
    const signed char* bSrc = B + (size_t)(bn + srow) * K + schunk * 16;

    auto STAGE = [&](int buf, int k0) {
        gload16(aSrc + k0, As[buf] + wid * 1024);
        gload16(bSrc + k0, Bs[buf] + wid * 1024);
    };

    int aOff[2], bOff[4];
#pragma unroll
    for (int mi = 0; mi < 2; mi++) {
        int ra = wm * 32 + mi * 16 + r16;
        aOff[mi] = ra * 64 + ((kq ^ ((ra >> 1) & 3)) * 16);
    }
#pragma unroll
    for (int ni = 0; ni < 4; ni++) {
        int rb = wn * 64 + ni * 16 + r16;
        bOff[ni] = rb * 64 + ((kq ^ ((rb >> 1) & 3)) * 16);
    }

    v4i acc[2][4];
#pragma unroll
    for (int i = 0; i < 2; i++)
#pragma unroll
        for (int j = 0; j < 4; j++) acc[i][j] = (v4i){0, 0, 0, 0};

    const int KT = K >> 6;
    STAGE(0, 0);
    for (int kt = 0; kt < KT; kt++) {
        const int cur = kt & 1;
        if (kt + 1 < KT) {
            STAGE(cur ^ 1, (kt + 1) << 6);
            asm volatile("s_waitcnt vmcnt(2)" ::: "memory");
        } else {
            asm volatile("s_waitcnt vmcnt(0)" ::: "memory");
        }
        __builtin_amdgcn_s_barrier();
        const signed char* as = As[cur];
        const signed char* bs = Bs[cur];
        v4i a[2], b[4];
#pragma unroll
        for (int mi = 0; mi < 2; mi++) a[mi] = *(const v4i*)(as + aOff[mi]);
#pragma unroll
        for (int ni = 0; ni < 4; ni++) b[ni] = *(const v4i*)(bs + bOff[ni]);
#pragma unroll
        for (int mi = 0; mi < 2; mi++)
#pragma unroll
            for (int ni = 0; ni < 4; ni++)
                acc[mi][ni] = __builtin_amdgcn_mfma_i32_16x16x64_i8(a[mi], b[ni], acc[mi][ni], 0, 0, 0);
        __builtin_amdgcn_s_barrier();
    }

    float v[2][4][4];
#pragma unroll
    for (int ni = 0; ni < 4; ni++) {
        int col = bn + wn * 64 + ni * 16 + r16;
        float ds = descale[col];
        int bv = bias[col];
#pragma unroll
        for (int mi = 0; mi < 2; mi++)
#pragma unroll
            for (int rr = 0; rr < 4; rr++)
                v[mi][ni][rr] = (float)(acc[mi][ni][rr] + bv) * ds;
    }

    const int wincol = bn + wn * 64;       // 64-aligned window base
    const int h = wincol / 192;            // wave-uniform head
    const int segb = wincol - h * 192;     // 0 / 64 / 128

    if (segb < 128) {                      // nope segment -> bf16 qn
#pragma unroll
        for (int mi = 0; mi < 2; mi++) {
            int rowb = bm + wm * 32 + mi * 16 + kq * 4;
#pragma unroll
            for (int rr = 0; rr < 4; rr++) {
                int t = rowb + rr;
#pragma unroll
                for (int ni = 0; ni < 4; ni++) {
                    int d = segb + ni * 16 + r16;
                    qn[(size_t)t * (H * NOPE) + h * NOPE + d] = f2bf(v[mi][ni][rr]);
                }
            }
        }
    } else {                               // rope segment -> f32 q_rope out
#pragma unroll
        for (int mi = 0; mi < 2; mi++) {
            int rowb = bm + wm * 32 + mi * 16 + kq * 4;
#pragma unroll
            for (int rr = 0; rr < 4; rr++) {
                int t = rowb + rr;
                const float* crow = cs + (size_t)t * ROPE;
                const float* srow2 = sn + (size_t)t * ROPE;
                float* orow = qrope + ((size_t)t * H + h) * ROPE;
#pragma unroll
                for (int ni = 0; ni < 2; ni++) {
                    int dp = ni * 16 + r16;          // [0,32)
                    float lo = v[mi][ni][rr];        // x[dp]
                    float hi = v[mi][ni + 2][rr];    // x[dp+32]
                    orow[dp]      = lo * crow[dp]      - hi * srow2[dp];
                    orow[dp + 32] = hi * crow[dp + 32] + lo * srow2[dp + 32];
                }
            }
        }
    }
}

// ---------------- post GEMM0 (bf16 out0 input, R15-verified) ----------------
__global__ __launch_bounds__(256) void post0_kernel(
    const unsigned short* __restrict__ out0,
    const float* __restrict__ gamma2,
    const float* __restrict__ gamma1, const float* __restrict__ beta1,
    const float* __restrict__ qs_p, const int* __restrict__ qo_p,
    const float* __restrict__ cs, const float* __restrict__ sn,
    const int* __restrict__ slot_mapping,
    float* __restrict__ out_kv, float* __restrict__ out_kv_rope,
    signed char* __restrict__ q8)
{
    __shared__ float2 red[4];
    const int t = blockIdx.x, tid = threadIdx.x;
    const unsigned short* row = out0 + (size_t)t * N0P;
    float c0 = bf2f(row[tid]), c1 = bf2f(row[256 + tid]);
    float ssc = c0 * c0 + c1 * c1;
    float qv[6];
    float ssq = 0.f;
#pragma unroll
    for (int i = 0; i < 6; i++) {
        float v = bf2f(row[KVL + ROPE + i * 256 + tid]);
        qv[i] = v;
        ssq += v * v;
    }
    float a = ssc, b2 = ssq;
#pragma unroll
    for (int off = 32; off > 0; off >>= 1) {
        a += __shfl_down(a, off);
        b2 += __shfl_down(b2, off);
    }
    if ((tid & 63) == 0) red[tid >> 6] = make_float2(a, b2);
    __syncthreads();
    float sc = red[0].x + red[1].x + red[2].x + red[3].x;
    float sq = red[0].y + red[1].y + red[2].y + red[3].y;
    float rsc = rsqrtf(sc / (float)KVL + 1e-6f);
    float rsq = rsqrtf(sq / (float)QL + 1e-6f);
    int slot = slot_mapping[t];
    out_kv[(size_t)slot * KVL + tid]       = c0 * rsc * gamma2[tid];
    out_kv[(size_t)slot * KVL + 256 + tid] = c1 * rsc * gamma2[256 + tid];
    if (tid < 64) {
        float xv = bf2f(row[KVL + tid]);
        float rot = (tid < 32) ? -bf2f(row[KVL + tid + 32]) : bf2f(row[KVL + tid - 32]);
        out_kv_rope[(size_t)slot * ROPE + tid] = xv * cs[t * ROPE + tid] + rot * sn[t * ROPE + tid];
    }
    float qs = qs_p[0], qo = (float)qo_p[0];
    signed char* q8r = q8 + (size_t)t * QL;
#pragma unroll
    for (int i = 0; i < 6; i++) {
        int j = i * 256 + tid;
        q8r[j] = (signed char)quanti(qv[i] * rsq * gamma1[j] + beta1[j], qs, qo);
    }
}

// ---------------- einsum thn,hnk->thk (R7-verified) -------------------------
__global__ __launch_bounds__(256, 2) void gemm_wkc_kernel(
    const unsigned short* __restrict__ Aq,   // [T][H*NOPE] bf16
    const unsigned short* __restrict__ Bw,   // [H][KVL][NOPE] bf16
    float* __restrict__ out)                 // [T][H][KVL]
{
    __shared__ __align__(16) unsigned short Qs[128 * 128];
    __shared__ __align__(16) unsigned short Ws[128 * 128];
    const int tid = threadIdx.x;
    const int lane = tid & 63, wid = tid >> 6;   // 4 waves
    const int wk = wid >> 1, wt = wid & 1;       // 2 (k) x 2 (t)
    const int r16 = lane & 15, kq = lane >> 4;

    const int bt = blockIdx.x * 128;   // token tile
    const int bk = blockIdx.y * 128;   // k tile
    const int h  = blockIdx.z;

    {
        const int lr = lane >> 4;           // 0..3
        const int lc = lane & 15;
#pragma unroll
        for (int p = 0; p < 8; p++) {
            int rr = wid * 32 + p * 4 + lr;
            int src_c = lc ^ (rr & 15);
            gload16(Aq + (size_t)(bt + rr) * (H * NOPE) + h * NOPE + src_c * 8,
                    (char*)Qs + (wid * 32 + p * 4) * 256 + lane * 16);
            gload16(Bw + ((size_t)h * KVL + bk + rr) * NOPE + src_c * 8,
                    (char*)Ws + (wid * 32 + p * 4) * 256 + lane * 16);
        }
    }
    asm volatile("s_waitcnt vmcnt(0)" ::: "memory");
    __builtin_amdgcn_s_barrier();

    v4f acc[4][4];
#pragma unroll
    for (int i = 0; i < 4; i++)
#pragma unroll
        for (int j = 0; j < 4; j++) acc[i][j] = (v4f){0.f, 0.f, 0.f, 0.f};

#pragma unroll
    for (int ks = 0; ks < 4; ks++) {
        v8s a[4], b[4];
#pragma unroll
        for (int mi = 0; mi < 4; mi++) {
            int ra = wk * 64 + mi * 16 + r16;
            int ch = (ks * 4 + kq) ^ (ra & 15);
            a[mi] = *(const v8s*)((const char*)Ws + ra * 256 + ch * 16);
        }
#pragma unroll
        for (int ni = 0; ni < 4; ni++) {
            int rb = wt * 64 + ni * 16 + r16;
            int ch = (ks * 4 + kq) ^ (rb & 15);
            b[ni] = *(const v8s*)((const char*)Qs + rb * 256 + ch * 16);
        }
#pragma unroll
        for (int mi = 0; mi < 4; mi++)
#pragma unroll
            for (int ni = 0; ni < 4; ni++)
                acc[mi][ni] = __builtin_amdgcn_mfma_f32_16x16x32_bf16(a[mi], b[ni], acc[mi][ni], 0, 0, 0);
    }

#pragma unroll
    for (int ni = 0; ni < 4; ni++) {
        int t = bt + wt * 64 + ni * 16 + r16;
        float* orow = out + ((size_t)t * H + h) * KVL + bk;
#pragma unroll
        for (int mi = 0; mi < 4; mi++) {
            int k0 = wk * 64 + mi * 16 + kq * 4;
            *(float4*)(orow + k0) = *(float4*)&acc[mi][ni];
        }
    }
}

extern "C" void kernel_launch(void* const* d_in, const int* in_sizes, int n_in,
                              void* d_out, int out_size, void* d_ws, size_t ws_size,
                              hipStream_t stream) {
    const float* hidden   = (const float*)d_in[0];
    const float* gamma0   = (const float*)d_in[1];
    const float* beta0    = (const float*)d_in[2];
    const int*   wdqkv    = (const int*)d_in[3];
    const float* descale0 = (const float*)d_in[4];
    const int*   bias0    = (const int*)d_in[5];
    const float* qs0      = (const float*)d_in[6];
    const int*   qo0      = (const int*)d_in[7];
    const float* gamma1   = (const float*)d_in[8];
    const float* beta1    = (const float*)d_in[9];
    const int*   wuq      = (const int*)d_in[10];
    const float* descale1 = (const float*)d_in[11];
    const int*   bias1    = (const int*)d_in[12];
    const float* qs1      = (const float*)d_in[13];
    const int*   qo1      = (const int*)d_in[14];
    const float* gamma2   = (const float*)d_in[15];
    const float* cos_t    = (const float*)d_in[16];
    const float* sin_t    = (const float*)d_in[17];
    const float* w_kc     = (const float*)d_in[18];
    const int*   slot_map = (const int*)d_in[21];

    float* out_q_rope  = (float*)d_out;                          // T*H*ROPE
    float* out_kv_rope = out_q_rope + (size_t)T_TOK * H * ROPE;  // SLOTS*ROPE
    float* out_q_nope  = out_kv_rope + (size_t)SLOTS * ROPE;     // T*H*KVL
    float* out_kv      = out_q_nope + (size_t)T_TOK * H * KVL;   // SLOTS*KVL

    char* ws = (char*)d_ws;
    char* ws_x8 = ws;                                            // T*HID
    char* ws_w0 = ws_x8 + (size_t)T_TOK * HID;                   // N0P*HID (padded)
    char* ws_w1 = ws_w0 + (size_t)N0P * HID;                     // NQ*QL
    unsigned short* ws_wkc = (unsigned short*)(ws_w1 + (size_t)NQ * QL);
    unsigned short* ws_out0 = (unsigned short*)((char*)ws_wkc + (size_t)H * KVL * NOPE * 2);  // T*N0P bf16
    signed char* ws_q8 = (signed char*)((char*)ws_out0 + (size_t)T_TOK * N0P * 2);
    unsigned short* ws_qn = (unsigned short*)((char*)ws_q8 + (size_t)T_TOK * QL);  // T*H*NOPE bf16

    // prep0: rmsnorm+quant of hidden + wdqkv pack (GEMM0's inputs only)
    prep_rms_kernel<<<T_TOK + PREP0_BLOCKS, 256, 0, stream>>>(
        hidden, gamma0, beta0, qs0, qo0, (unsigned int*)ws_x8, wdqkv, (unsigned int*)ws_w0);

    // GEMM0 + trailing prep (w1 pack, wkc transpose, kv-tail zero)
    gemm_i8_db_kernel<<<NGEMM0 + PREP_TRAIL, 512, 0, stream>>>(
        (const signed char*)ws_x8, (const signed char*)ws_w0, bias0, descale0, ws_out0,
        T_TOK, N0, N0P, HID, NGEMM0,
        wuq, w_kc, (unsigned int*)ws_w1, ws_wkc,
        out_kv + (size_t)T_TOK * KVL, out_kv_rope + (size_t)T_TOK * ROPE);

    // post0
    post0_kernel<<<T_TOK, 256, 0, stream>>>(ws_out0, gamma2, gamma1, beta1, qs1, qo1,
                                            cos_t, sin_t, slot_map, out_kv, out_kv_rope, ws_q8);

    // GEMM1 with fused post1: writes ws_qn (bf16) + out_q_rope directly
    gemm1_fused_kernel<<<(T_TOK / 128) * (NQ / 128), 512, 0, stream>>>(
        ws_q8, (const signed char*)ws_w1, bias1, descale1, cos_t, sin_t,
        ws_qn, out_q_rope, QL);

    // einsum: grid (t-tiles, k-tiles, heads)
    gemm_wkc_kernel<<<dim3(T_TOK / 128, KVL / 128, H), 256, 0, stream>>>(ws_qn, ws_wkc, out_q_nope);
}

// Round 20
// 225.400 us; speedup vs baseline: 1.0184x; 1.0184x over previous
//
#include <hip/hip_runtime.h>
#include <hip/hip_bf16.h>
#include <stdint.h>

#define T_TOK 4096
#define HID   7168
#define N0    2112
#define N0P   2176
#define QL    1536
#define KVL   512
#define ROPE  64
#define NQ    3072
#define H     16
#define NOPE  128
#define SLOTS 16384

#define N40 ((N0 * HID) / 4)
#define N41 ((NQ * QL) / 4)
#define NWKC (H * KVL * NOPE)
#define PREP0_BLOCKS ((N40 + 255) / 256)
#define ZKV4  ((SLOTS - T_TOK) * KVL / 4)
#define ZKVR4 ((SLOTS - T_TOK) * ROPE / 4)
#define PTOT (N41 + NWKC + ZKV4 + ZKVR4)
#define PREP_TRAIL 1024
#define NGEMM0 ((T_TOK / 128) * (N0P / 128))

typedef int   v4i __attribute__((ext_vector_type(4)));
typedef short v8s __attribute__((ext_vector_type(8)));
typedef float v4f __attribute__((ext_vector_type(4)));

typedef const __attribute__((address_space(1))) void g_void_t;
typedef __attribute__((address_space(3))) void lds_void_t;

__device__ __forceinline__ void gload16(const void* gp, void* lp) {
    __builtin_amdgcn_global_load_lds((g_void_t*)gp, (lds_void_t*)lp, 16, 0, 0);
}

__device__ __forceinline__ int quanti(float v, float qs, float qo) {
    float r = rintf(v / qs + qo);          // round half-to-even, matches jnp.round
    r = fminf(127.f, fmaxf(-128.f, r));
    return (int)r;
}

__device__ __forceinline__ unsigned int pack4(int a, int b, int c, int d) {
    return (unsigned int)(a & 255) | ((unsigned int)(b & 255) << 8) |
           ((unsigned int)(c & 255) << 16) | ((unsigned int)(d & 255) << 24);
}

__device__ __forceinline__ unsigned short f2bf(float v) {
    __hip_bfloat16 b = __float2bfloat16(v);
    return *reinterpret_cast<unsigned short*>(&b);
}

__device__ __forceinline__ float bf2f(unsigned short u) {
    unsigned int x = ((unsigned int)u) << 16;
    return *reinterpret_cast<float*>(&x);
}

// -- prep0: rms+quant rows [0,T) | wdqkv pack (only what GEMM0 needs) --------
__global__ __launch_bounds__(256) void prep_rms_kernel(
    const float* __restrict__ x, const float* __restrict__ g, const float* __restrict__ b,
    const float* __restrict__ qs_p, const int* __restrict__ qo_p,
    unsigned int* __restrict__ x8,
    const int* __restrict__ wdqkv, unsigned int* __restrict__ w0)
{
    const int tid = threadIdx.x;
    if (blockIdx.x >= T_TOK) {
        int i = (blockIdx.x - T_TOK) * 256 + tid;
        if (i < N40) {
            int4 v = ((const int4*)wdqkv)[i];
            w0[i] = pack4(v.x, v.y, v.z, v.w);
        }
        return;
    }
    // rmsnorm + quant row
    __shared__ float red[4];
    const int t = blockIdx.x;
    const float4* xr = (const float4*)(x + (size_t)t * HID);
    float4 vs[7];
    float ss = 0.f;
#pragma unroll
    for (int i = 0; i < 7; i++) {
        float4 v = xr[i * 256 + tid];
        vs[i] = v;
        ss += v.x * v.x + v.y * v.y + v.z * v.z + v.w * v.w;
    }
#pragma unroll
    for (int off = 32; off > 0; off >>= 1) ss += __shfl_down(ss, off);
    if ((tid & 63) == 0) red[tid >> 6] = ss;
    __syncthreads();
    float s = red[0] + red[1] + red[2] + red[3];
    float rs = rsqrtf(s / (float)HID + 1e-6f);
    float qs = qs_p[0];
    float qo = (float)qo_p[0];
    const float4* gr = (const float4*)g;
    const float4* br = (const float4*)b;
    unsigned int* orow = x8 + (size_t)t * (HID / 4);
#pragma unroll
    for (int i = 0; i < 7; i++) {
        int j = i * 256 + tid;
        float4 v = vs[i], gg = gr[j], bb = br[j];
        int q0 = quanti(v.x * rs * gg.x + bb.x, qs, qo);
        int q1 = quanti(v.y * rs * gg.y + bb.y, qs, qo);
        int q2 = quanti(v.z * rs * gg.z + bb.z, qs, qo);
        int q3 = quanti(v.w * rs * gg.w + bb.w, qs, qo);
        orow[j] = pack4(q0, q1, q2, q3);
    }
}

// ---------------- GEMM0: i8, BK=64, double-buffered (R15-verified), bf16 C -
// BM=BN=128, BK=64, 512 threads = 8 waves (2x4), wave tile 64x32.
// Blocks [ngemm, gridDim.x): trailing prep (w1 pack + wkc transpose + kv-tail
// zero) grid-striding while the GEMM blocks run -- GEMM0 is latency-bound at
// 15% HBM so this guest traffic hides entirely. Their consumers (GEMM1, wkc
// einsum) are stream-ordered after this kernel.
__global__ __launch_bounds__(512, 8) void gemm_i8_db_kernel(
    const signed char* __restrict__ A, const signed char* __restrict__ B,
    const int* __restrict__ bias, const float* __restrict__ descale,
    unsigned short* __restrict__ C, int M, int N, int Np, int K, int ntn, int ngemm,
    const int* __restrict__ wuq, const float* __restrict__ wkc,
    unsigned int* __restrict__ w1o, unsigned short* __restrict__ wkcb,
    float* __restrict__ kv_tail, float* __restrict__ kvr_tail)
{
    __shared__ __align__(16) signed char As[2][128 * 64];
    __shared__ __align__(16) signed char Bs[2][128 * 64];
    const int tid = threadIdx.x;

    if (blockIdx.x >= ngemm) {             // trailing prep blocks
        const int stride = (gridDim.x - ngemm) * 512;
        for (int i = (blockIdx.x - ngemm) * 512 + tid; i < PTOT; i += stride) {
            int j = i;
            if (j < N41) {
                int4 v = ((const int4*)wuq)[j];
                w1o[j] = pack4(v.x, v.y, v.z, v.w);
            } else if ((j -= N41) < NWKC) {
                int n = j & (NOPE - 1);
                int k = (j >> 7) & (KVL - 1);
                int h = j >> 16;
                wkcb[j] = f2bf(wkc[((size_t)h * NOPE + n) * KVL + k]);
            } else if ((j -= NWKC) < ZKV4) {
                ((float4*)kv_tail)[j] = make_float4(0.f, 0.f, 0.f, 0.f);
            } else {
                j -= ZKV4;
                ((float4*)kvr_tail)[j] = make_float4(0.f, 0.f, 0.f, 0.f);
            }
        }
        return;
    }

    const int lane = tid & 63, wid = tid >> 6;     // 8 waves
    const int wm = wid >> 2, wn = wid & 3;         // 2 x 4
    const int r16 = lane & 15, kq = lane >> 4;     // kq = 16B chunk 0..3

    // XCD-aware bijective swizzle over the ngemm GEMM blocks only
    const int nwg = ngemm;
    const int q = nwg >> 3, r = nwg & 7;
    const int xcd = blockIdx.x & 7, idx = blockIdx.x >> 3;
    const int wg = (xcd < r ? xcd * (q + 1) : r * (q + 1) + (xcd - r) * q) + idx;
    const int bm = (wg / ntn) * 128, bn = (wg % ntn) * 128;

    const int srow = tid >> 2;
    const int schunk = (tid & 3) ^ ((srow >> 1) & 3);
    const signed char* aSrc = A + (size_t)(bm + srow) * K + schunk * 16;
    const signed char* bSrc = B + (size_t)(bn + srow) * K + schunk * 16;

    auto STAGE = [&](int buf, int k0) {
        gload16(aSrc + k0, As[buf] + wid * 1024);
        gload16(bSrc + k0, Bs[buf] + wid * 1024);
    };

    int aOff[4], bOff[2];
#pragma unroll
    for (int mi = 0; mi < 4; mi++) {
        int ra = wm * 64 + mi * 16 + r16;
        aOff[mi] = ra * 64 + ((kq ^ ((ra >> 1) & 3)) * 16);
    }
#pragma unroll
    for (int ni = 0; ni < 2; ni++) {
        int rb = wn * 32 + ni * 16 + r16;
        bOff[ni] = rb * 64 + ((kq ^ ((rb >> 1) & 3)) * 16);
    }

    v4i acc[4][2];
#pragma unroll
    for (int i = 0; i < 4; i++)
#pragma unroll
        for (int j = 0; j < 2; j++) acc[i][j] = (v4i){0, 0, 0, 0};

    const int KT = K >> 6;
    STAGE(0, 0);
    for (int kt = 0; kt < KT; kt++) {
        const int cur = kt & 1;
        if (kt + 1 < KT) {
            STAGE(cur ^ 1, (kt + 1) << 6);
            asm volatile("s_waitcnt vmcnt(2)" ::: "memory");
        } else {
            asm volatile("s_waitcnt vmcnt(0)" ::: "memory");
        }
        __builtin_amdgcn_s_barrier();
        const signed char* as = As[cur];
        const signed char* bs = Bs[cur];
        v4i a[4], b[2];
#pragma unroll
        for (int mi = 0; mi < 4; mi++) a[mi] = *(const v4i*)(as + aOff[mi]);
#pragma unroll
        for (int ni = 0; ni < 2; ni++) b[ni] = *(const v4i*)(bs + bOff[ni]);
#pragma unroll
        for (int mi = 0; mi < 4; mi++)
#pragma unroll
            for (int ni = 0; ni < 2; ni++)
                acc[mi][ni] = __builtin_amdgcn_mfma_i32_16x16x64_i8(a[mi], b[ni], acc[mi][ni], 0, 0, 0);
        __builtin_amdgcn_s_barrier();
    }

#pragma unroll
    for (int ni = 0; ni < 2; ni++) {
        int col = bn + wn * 32 + ni * 16 + r16;
        int cc = col < N ? col : 0;
        float ds = descale[cc];
        int bv = bias[cc];
#pragma unroll
        for (int mi = 0; mi < 4; mi++) {
            int rowb = bm + wm * 64 + mi * 16 + kq * 4;
#pragma unroll
            for (int rr = 0; rr < 4; rr++) {
                C[(size_t)(rowb + rr) * Np + col] = f2bf((float)(acc[mi][ni][rr] + bv) * ds);
            }
        }
    }
}

// ---------------- GEMM1 + fused post1 epilogue (R13/R15-verified) ----------
__global__ __launch_bounds__(512, 8) void gemm1_fused_kernel(
    const signed char* __restrict__ A, const signed char* __restrict__ B,
    const int* __restrict__ bias, const float* __restrict__ descale,
    const float* __restrict__ cs, const float* __restrict__ sn,
    unsigned short* __restrict__ qn, float* __restrict__ qrope,
    int K, int ntn)
{
    __shared__ __align__(16) signed char As[2][128 * 64];
    __shared__ __align__(16) signed char Bs[2][128 * 64];
    const int tid = threadIdx.x;
    const int lane = tid & 63, wid = tid >> 6;     // 8 waves
    const int wm = wid >> 1, wn = wid & 1;         // 4(M) x 2(N)
    const int r16 = lane & 15, kq = lane >> 4;

    const int nwg = gridDim.x;
    const int q = nwg >> 3, r = nwg & 7;
    const int xcd = blockIdx.x & 7, idx = blockIdx.x >> 3;
    const int wg = (xcd < r ? xcd * (q + 1) : r * (q + 1) + (xcd - r) * q) + idx;
    const int bm = (wg / ntn) * 128, bn = (wg % ntn) * 128;

    const int srow = tid >> 2;
    const int schunk = (tid & 3) ^ ((srow >> 1) & 3);
    const signed char* aSrc = A + (size_t)(bm + srow) * K + schunk * 16;
    const signed char* bSrc = B + (size_t)(bn + srow) * K + schunk * 16;

    auto STAGE = [&](int buf, int k0) {
        gload16(aSrc + k0, As[buf] + wid * 1024);
        gload16(bSrc + k0, Bs[buf] + wid * 1024);
    };

    int aOff[2], bOff[4];
#pragma unroll
    for (int mi = 0; mi < 2; mi++) {
        int ra = wm * 32 + mi * 16 + r16;
        aOff[mi] = ra * 64 + ((kq ^ ((ra >> 1) & 3)) * 16);
    }
#pragma unroll
    for (int ni = 0; ni < 4; ni++) {
        int rb = wn * 64 + ni * 16 + r16;
        bOff[ni] = rb * 64 + ((kq ^ ((rb >> 1) & 3)) * 16);
    }

    v4i acc[2][4];
#pragma unroll
    for (int i = 0; i < 2; i++)
#pragma unroll
        for (int j = 0; j < 4; j++) acc[i][j] = (v4i){0, 0, 0, 0};

    const int KT = K >> 6;
    STAGE(0, 0);
    for (int kt = 0; kt < KT; kt++) {
        const int cur = kt & 1;
        if (kt + 1 < KT) {
            STAGE(cur ^ 1, (kt + 1) << 6);
            asm volatile("s_waitcnt vmcnt(2)" ::: "memory");
        } else {
            asm volatile("s_waitcnt vmcnt(0)" ::: "memory");
        }
        __builtin_amdgcn_s_barrier();
        const signed char* as = As[cur];
        const signed char* bs = Bs[cur];
        v4i a[2], b[4];
#pragma unroll
        for (int mi = 0; mi < 2; mi++) a[mi] = *(const v4i*)(as + aOff[mi]);
#pragma unroll
        for (int ni = 0; ni < 4; ni++) b[ni] = *(const v4i*)(bs + bOff[ni]);
#pragma unroll
        for (int mi = 0; mi < 2; mi++)
#pragma unroll
            for (int ni = 0; ni < 4; ni++)
                acc[mi][ni] = __builtin_amdgcn_mfma_i32_16x16x64_i8(a[mi], b[ni], acc[mi][ni], 0, 0, 0);
        __builtin_amdgcn_s_barrier();
    }

    float v[2][4][4];
#pragma unroll
    for (int ni = 0; ni < 4; ni++) {
        int col = bn + wn * 64 + ni * 16 + r16;
        float ds = descale[col];
        int bv = bias[col];
#pragma unroll
        for (int mi = 0; mi < 2; mi++)
#pragma unroll
            for (int rr = 0; rr < 4; rr++)
                v[mi][ni][rr] = (float)(acc[mi][ni][rr] + bv) * ds;
    }

    const int wincol = bn + wn * 64;       // 64-aligned window base
    const int h = wincol / 192;            // wave-uniform head
    const int segb = wincol - h * 192;     // 0 / 64 / 128

    if (segb < 128) {                      // nope segment -> bf16 qn
#pragma unroll
        for (int mi = 0; mi < 2; mi++) {
            int rowb = bm + wm * 32 + mi * 16 + kq * 4;
#pragma unroll
            for (int rr = 0; rr < 4; rr++) {
                int t = rowb + rr;
#pragma unroll
                for (int ni = 0; ni < 4; ni++) {
                    int d = segb + ni * 16 + r16;
                    qn[(size_t)t * (H * NOPE) + h * NOPE + d] = f2bf(v[mi][ni][rr]);
                }
            }
        }
    } else {                               // rope segment -> f32 q_rope out
#pragma unroll
        for (int mi = 0; mi < 2; mi++) {
            int rowb = bm + wm * 32 + mi * 16 + kq * 4;
#pragma unroll
            for (int rr = 0; rr < 4; rr++) {
                int t = rowb + rr;
                const float* crow = cs + (size_t)t * ROPE;
                const float* srow2 = sn + (size_t)t * ROPE;
                float* orow = qrope + ((size_t)t * H + h) * ROPE;
#pragma unroll
                for (int ni = 0; ni < 2; ni++) {
                    int dp = ni * 16 + r16;          // [0,32)
                    float lo = v[mi][ni][rr];        // x[dp]
                    float hi = v[mi][ni + 2][rr];    // x[dp+32]
                    orow[dp]      = lo * crow[dp]      - hi * srow2[dp];
                    orow[dp + 32] = hi * crow[dp + 32] + lo * srow2[dp + 32];
                }
            }
        }
    }
}

// ---------------- post GEMM0 (bf16 out0 input, R15-verified) ----------------
__global__ __launch_bounds__(256) void post0_kernel(
    const unsigned short* __restrict__ out0,
    const float* __restrict__ gamma2,
    const float* __restrict__ gamma1, const float* __restrict__ beta1,
    const float* __restrict__ qs_p, const int* __restrict__ qo_p,
    const float* __restrict__ cs, const float* __restrict__ sn,
    const int* __restrict__ slot_mapping,
    float* __restrict__ out_kv, float* __restrict__ out_kv_rope,
    signed char* __restrict__ q8)
{
    __shared__ float2 red[4];
    const int t = blockIdx.x, tid = threadIdx.x;
    const unsigned short* row = out0 + (size_t)t * N0P;
    float c0 = bf2f(row[tid]), c1 = bf2f(row[256 + tid]);
    float ssc = c0 * c0 + c1 * c1;
    float qv[6];
    float ssq = 0.f;
#pragma unroll
    for (int i = 0; i < 6; i++) {
        float v = bf2f(row[KVL + ROPE + i * 256 + tid]);
        qv[i] = v;
        ssq += v * v;
    }
    float a = ssc, b2 = ssq;
#pragma unroll
    for (int off = 32; off > 0; off >>= 1) {
        a += __shfl_down(a, off);
        b2 += __shfl_down(b2, off);
    }
    if ((tid & 63) == 0) red[tid >> 6] = make_float2(a, b2);
    __syncthreads();
    float sc = red[0].x + red[1].x + red[2].x + red[3].x;
    float sq = red[0].y + red[1].y + red[2].y + red[3].y;
    float rsc = rsqrtf(sc / (float)KVL + 1e-6f);
    float rsq = rsqrtf(sq / (float)QL + 1e-6f);
    int slot = slot_mapping[t];
    out_kv[(size_t)slot * KVL + tid]       = c0 * rsc * gamma2[tid];
    out_kv[(size_t)slot * KVL + 256 + tid] = c1 * rsc * gamma2[256 + tid];
    if (tid < 64) {
        float xv = bf2f(row[KVL + tid]);
        float rot = (tid < 32) ? -bf2f(row[KVL + tid + 32]) : bf2f(row[KVL + tid - 32]);
        out_kv_rope[(size_t)slot * ROPE + tid] = xv * cs[t * ROPE + tid] + rot * sn[t * ROPE + tid];
    }
    float qs = qs_p[0], qo = (float)qo_p[0];
    signed char* q8r = q8 + (size_t)t * QL;
#pragma unroll
    for (int i = 0; i < 6; i++) {
        int j = i * 256 + tid;
        q8r[j] = (signed char)quanti(qv[i] * rsq * gamma1[j] + beta1[j], qs, qo);
    }
}

// ---------------- einsum thn,hnk->thk (R7-verified) -------------------------
__global__ __launch_bounds__(256, 2) void gemm_wkc_kernel(
    const unsigned short* __restrict__ Aq,   // [T][H*NOPE] bf16
    const unsigned short* __restrict__ Bw,   // [H][KVL][NOPE] bf16
    float* __restrict__ out)                 // [T][H][KVL]
{
    __shared__ __align__(16) unsigned short Qs[128 * 128];
    __shared__ __align__(16) unsigned short Ws[128 * 128];
    const int tid = threadIdx.x;
    const int lane = tid & 63, wid = tid >> 6;   // 4 waves
    const int wk = wid >> 1, wt = wid & 1;       // 2 (k) x 2 (t)
    const int r16 = lane & 15, kq = lane >> 4;

    const int bt = blockIdx.x * 128;   // token tile
    const int bk = blockIdx.y * 128;   // k tile
    const int h  = blockIdx.z;

    {
        const int lr = lane >> 4;           // 0..3
        const int lc = lane & 15;
#pragma unroll
        for (int p = 0; p < 8; p++) {
            int rr = wid * 32 + p * 4 + lr;
            int src_c = lc ^ (rr & 15);
            gload16(Aq + (size_t)(bt + rr) * (H * NOPE) + h * NOPE + src_c * 8,
                    (char*)Qs + (wid * 32 + p * 4) * 256 + lane * 16);
            gload16(Bw + ((size_t)h * KVL + bk + rr) * NOPE + src_c * 8,
                    (char*)Ws + (wid * 32 + p * 4) * 256 + lane * 16);
        }
    }
    asm volatile("s_waitcnt vmcnt(0)" ::: "memory");
    __builtin_amdgcn_s_barrier();

    v4f acc[4][4];
#pragma unroll
    for (int i = 0; i < 4; i++)
#pragma unroll
        for (int j = 0; j < 4; j++) acc[i][j] = (v4f){0.f, 0.f, 0.f, 0.f};

#pragma unroll
    for (int ks = 0; ks < 4; ks++) {
        v8s a[4], b[4];
#pragma unroll
        for (int mi = 0; mi < 4; mi++) {
            int ra = wk * 64 + mi * 16 + r16;
            int ch = (ks * 4 + kq) ^ (ra & 15);
            a[mi] = *(const v8s*)((const char*)Ws + ra * 256 + ch * 16);
        }
#pragma unroll
        for (int ni = 0; ni < 4; ni++) {
            int rb = wt * 64 + ni * 16 + r16;
            int ch = (ks * 4 + kq) ^ (rb & 15);
            b[ni] = *(const v8s*)((const char*)Qs + rb * 256 + ch * 16);
        }
#pragma unroll
        for (int mi = 0; mi < 4; mi++)
#pragma unroll
            for (int ni = 0; ni < 4; ni++)
                acc[mi][ni] = __builtin_amdgcn_mfma_f32_16x16x32_bf16(a[mi], b[ni], acc[mi][ni], 0, 0, 0);
    }

#pragma unroll
    for (int ni = 0; ni < 4; ni++) {
        int t = bt + wt * 64 + ni * 16 + r16;
        float* orow = out + ((size_t)t * H + h) * KVL + bk;
#pragma unroll
        for (int mi = 0; mi < 4; mi++) {
            int k0 = wk * 64 + mi * 16 + kq * 4;
            *(float4*)(orow + k0) = *(float4*)&acc[mi][ni];
        }
    }
}

extern "C" void kernel_launch(void* const* d_in, const int* in_sizes, int n_in,
                              void* d_out, int out_size, void* d_ws, size_t ws_size,
                              hipStream_t stream) {
    const float* hidden   = (const float*)d_in[0];
    const float* gamma0   = (const float*)d_in[1];
    const float* beta0    = (const float*)d_in[2];
    const int*   wdqkv    = (const int*)d_in[3];
    const float* descale0 = (const float*)d_in[4];
    const int*   bias0    = (const int*)d_in[5];
    const float* qs0      = (const float*)d_in[6];
    const int*   qo0      = (const int*)d_in[7];
    const float* gamma1   = (const float*)d_in[8];
    const float* beta1    = (const float*)d_in[9];
    const int*   wuq      = (const int*)d_in[10];
    const float* descale1 = (const float*)d_in[11];
    const int*   bias1    = (const int*)d_in[12];
    const float* qs1      = (const float*)d_in[13];
    const int*   qo1      = (const int*)d_in[14];
    const float* gamma2   = (const float*)d_in[15];
    const float* cos_t    = (const float*)d_in[16];
    const float* sin_t    = (const float*)d_in[17];
    const float* w_kc     = (const float*)d_in[18];
    const int*   slot_map = (const int*)d_in[21];

    float* out_q_rope  = (float*)d_out;                          // T*H*ROPE
    float* out_kv_rope = out_q_rope + (size_t)T_TOK * H * ROPE;  // SLOTS*ROPE
    float* out_q_nope  = out_kv_rope + (size_t)SLOTS * ROPE;     // T*H*KVL
    float* out_kv      = out_q_nope + (size_t)T_TOK * H * KVL;   // SLOTS*KVL

    char* ws = (char*)d_ws;
    char* ws_x8 = ws;                                            // T*HID
    char* ws_w0 = ws_x8 + (size_t)T_TOK * HID;                   // N0P*HID (padded)
    char* ws_w1 = ws_w0 + (size_t)N0P * HID;                     // NQ*QL
    unsigned short* ws_wkc = (unsigned short*)(ws_w1 + (size_t)NQ * QL);
    unsigned short* ws_out0 = (unsigned short*)((char*)ws_wkc + (size_t)H * KVL * NOPE * 2);  // T*N0P bf16
    signed char* ws_q8 = (signed char*)((char*)ws_out0 + (size_t)T_TOK * N0P * 2);
    unsigned short* ws_qn = (unsigned short*)((char*)ws_q8 + (size_t)T_TOK * QL);  // T*H*NOPE bf16

    // prep0: rmsnorm+quant of hidden + wdqkv pack (GEMM0's inputs only)
    prep_rms_kernel<<<T_TOK + PREP0_BLOCKS, 256, 0, stream>>>(
        hidden, gamma0, beta0, qs0, qo0, (unsigned int*)ws_x8, wdqkv, (unsigned int*)ws_w0);

    // GEMM0 + trailing prep (w1 pack, wkc transpose, kv-tail zero)
    gemm_i8_db_kernel<<<NGEMM0 + PREP_TRAIL, 512, 0, stream>>>(
        (const signed char*)ws_x8, (const signed char*)ws_w0, bias0, descale0, ws_out0,
        T_TOK, N0, N0P, HID, N0P / 128, NGEMM0,
        wuq, w_kc, (unsigned int*)ws_w1, ws_wkc,
        out_kv + (size_t)T_TOK * KVL, out_kv_rope + (size_t)T_TOK * ROPE);

    // post0
    post0_kernel<<<T_TOK, 256, 0, stream>>>(ws_out0, gamma2, gamma1, beta1, qs1, qo1,
                                            cos_t, sin_t, slot_map, out_kv, out_kv_rope, ws_q8);

    // GEMM1 with fused post1: writes ws_qn (bf16) + out_q_rope directly
    gemm1_fused_kernel<<<(T_TOK / 128) * (NQ / 128), 512, 0, stream>>>(
        ws_q8, (const signed char*)ws_w1, bias1, descale1, cos_t, sin_t,
        ws_qn, out_q_rope, QL, NQ / 128);

    // einsum: grid (t-tiles, k-tiles, heads)
    gemm_wkc_kernel<<<dim3(T_TOK / 128, KVL / 128, H), 256, 0, stream>>>(ws_qn, ws_wkc, out_q_nope);
}